// Round 7
// baseline (353.199 us; speedup 1.0000x reference)
//
#include <hip/hip_runtime.h>
#include <hip/hip_bf16.h>

// Switch-Transformer FFN, top-1 routing. B=4,S=4096,D=1024,F=2048,E=8.
// Pipeline: router_logits(+x->bf16) | bucketize | W1/W2 transpose->bf16 |
// grouped GEMM1 (gathered A, GELU, h bf16 dense by slot) |
// grouped GEMM2 (dense A, scale epi, scatter fp32).
// GEMM: 256x256, BK=32 subtiles, ring-4 LDS, frag-register double-buffer:
// tile T+1's 12 ds_read_b128 issue BEFORE tile T's 32-MFMA cluster (compiler
// emits counted lgkmcnt, LDS pipe overlaps MFMA pipe within the wave).
// One barrier + one counted vmcnt(4) per subtile. 0-conflict XOR swizzle.

typedef __attribute__((ext_vector_type(8))) short short8;
typedef __attribute__((ext_vector_type(4))) float f32x4;

struct __align__(8) us4 { unsigned short x, y, z, w; };

__device__ __forceinline__ void gload16(const void* g, void* l) {
  __builtin_amdgcn_global_load_lds(
      (const __attribute__((address_space(1))) unsigned int*)g,
      (__attribute__((address_space(3))) unsigned int*)l, 16, 0, 0);
}

__device__ __forceinline__ unsigned short f2b(float f) {
  union { float f; unsigned u; } v; v.f = f;
  unsigned r = v.u + 0x7FFFu + ((v.u >> 16) & 1u);   // RNE
  return (unsigned short)(r >> 16);
}

// ---------------- router: logits, softmax top-1, expert id, x->bf16 ---------
__global__ __launch_bounds__(256) void router_logits(
    const float* __restrict__ x, const float* __restrict__ Wr,
    const float* __restrict__ br, float* __restrict__ wts,
    int* __restrict__ eidx, unsigned short* __restrict__ xb)
{
  const int lane = threadIdx.x & 63;
  const int wid  = threadIdx.x >> 6;
  const int t = blockIdx.x * 4 + wid;

  const float4* x4 = (const float4*)(x + (size_t)t * 1024);
  float acc[8];
#pragma unroll
  for (int e = 0; e < 8; ++e) acc[e] = 0.f;
#pragma unroll
  for (int i = 0; i < 4; ++i) {
    float4 v = x4[lane + 64 * i];
    const int d = (lane + 64 * i) * 4;
    const float* wr = Wr + (size_t)d * 8;
    float xs[4] = {v.x, v.y, v.z, v.w};
    us4 o;
    o.x = f2b(v.x); o.y = f2b(v.y); o.z = f2b(v.z); o.w = f2b(v.w);
    *(us4*)(xb + (size_t)t * 1024 + (size_t)(lane + 64 * i) * 4) = o;
#pragma unroll
    for (int j = 0; j < 4; ++j) {
      float4 w0 = *(const float4*)(wr + j * 8);
      float4 w1 = *(const float4*)(wr + j * 8 + 4);
      acc[0] += xs[j] * w0.x; acc[1] += xs[j] * w0.y;
      acc[2] += xs[j] * w0.z; acc[3] += xs[j] * w0.w;
      acc[4] += xs[j] * w1.x; acc[5] += xs[j] * w1.y;
      acc[6] += xs[j] * w1.z; acc[7] += xs[j] * w1.w;
    }
  }
#pragma unroll
  for (int e = 0; e < 8; ++e) {
    float v = acc[e];
#pragma unroll
    for (int m = 32; m; m >>= 1) v += __shfl_xor(v, m, 64);
    acc[e] = v;
  }
  if (lane == 0) {
    float lg[8];
#pragma unroll
    for (int e = 0; e < 8; ++e) lg[e] = acc[e] + br[e];
    float mx = lg[0]; int bi = 0;
#pragma unroll
    for (int e = 1; e < 8; ++e) if (lg[e] > mx) { mx = lg[e]; bi = e; }  // first-max == argmax
    float s = 0.f;
#pragma unroll
    for (int e = 0; e < 8; ++e) s += expf(lg[e] - mx);
    wts[t]  = 1.0f / s;
    eidx[t] = bi;
  }
}

// ---------------- bucketize ----------
__global__ __launch_bounds__(256) void bucketize(
    const int* __restrict__ eidx, int* __restrict__ cnt, int* __restrict__ list)
{
  __shared__ int lcnt[8], base[8];
  const int tid = threadIdx.x;
  if (tid < 8) lcnt[tid] = 0;
  __syncthreads();
  const int t = blockIdx.x * 256 + tid;
  const int e = eidx[t];
  const int lpos = atomicAdd(&lcnt[e], 1);
  __syncthreads();
  if (tid < 8) base[tid] = atomicAdd(&cnt[tid], lcnt[tid]);
  __syncthreads();
  list[e * 16384 + base[e] + lpos] = t;
}

// ---------------- W[k][n] fp32 -> Wt[n][k] bf16 ----------
__global__ __launch_bounds__(256) void transpose_cvt(
    const float* __restrict__ W, unsigned short* __restrict__ Wt, int K, int N)
{
  __shared__ float tl[64][65];
  const int e = blockIdx.z;
  const float* Wp = W + (size_t)e * K * N;
  unsigned short* Wtp = Wt + (size_t)e * K * N;
  const int k0 = blockIdx.y * 64, n0 = blockIdx.x * 64;
  const int r = threadIdx.x >> 4, c4 = (threadIdx.x & 15) * 4;
#pragma unroll
  for (int i = 0; i < 4; ++i) {
    float4 v = *(const float4*)(Wp + (size_t)(k0 + r + i * 16) * N + n0 + c4);
    tl[r + i * 16][c4 + 0] = v.x; tl[r + i * 16][c4 + 1] = v.y;
    tl[r + i * 16][c4 + 2] = v.z; tl[r + i * 16][c4 + 3] = v.w;
  }
  __syncthreads();
#pragma unroll
  for (int i = 0; i < 4; ++i) {
    const int n = r + i * 16;
    us4 o;
    o.x = f2b(tl[c4 + 0][n]); o.y = f2b(tl[c4 + 1][n]);
    o.z = f2b(tl[c4 + 2][n]); o.w = f2b(tl[c4 + 3][n]);
    *(us4*)(Wtp + (size_t)(n0 + n) * K + k0 + c4) = o;
  }
}

// ---------------- grouped GEMM: 256x256, ring-4, frag-prefetch pipeline -----
// LDS: A ring 4x[256][32]bf16 @0; B ring @65536; tok@131072 wt@132096.
// Swizzle (measured 0-conflict): 16B-slot c of row r holds chunk c^((r>>1)&3).
// Iter T: { 12 ds_read frags(T+1) -> nxt regs | STG(T+3) | sched_bar |
//   setprio(1) 32 MFMA on cur regs (compiler waits lgkmcnt(12), the 12
//   frag(T+1) reads + 4 gloads run under MFMA) setprio(0) | vmcnt(4) | bar }.
// Certification: vmcnt(4) at iter T leaves only stage(T+3) outstanding ->
// tiles <= T+2 certified; so at iter T+1 top, frags(T+2) reads are safe.
// Slot audit: read slot (T+1)&3 vs write slot (T+3)&3=(T-1)&3 differ by 2
// mod 4; reads of a slot certify (lgkm, pre-barrier) before its rewrite.
template <int K, int N, int EPI, int LOGNB>
__global__ __launch_bounds__(512, 2) void gemm_moe8(
    const unsigned short* __restrict__ A,    // EPI1: xb[16384][K] (token rows)
                                             // EPI2: h [16384][K] (slot rows)
    const unsigned short* __restrict__ Bt,   // [8][N][K] bf16
    const float* __restrict__ bias,          // [8][N]
    const int* __restrict__ cnt, const int* __restrict__ list,
    const float* __restrict__ wts, void* __restrict__ outp)
{
  constexpr int NT = K / 32;
  constexpr int NB = 1 << LOGNB;
  extern __shared__ char lds[];
  int*   tok_s = (int*)(lds + 131072);
  float* wt_s  = (float*)(lds + 132096);

  // ---- decode: XCD-chunked p -> (expert, mb, nb); nb fast (A-panel reuse)
  const int q = gridDim.x >> 3;
  const int p = ((int)blockIdx.x & 7) * q + ((int)blockIdx.x >> 3);
  int e = -1, pre = 0, cnte = 0, loc = p;
#pragma unroll
  for (int i = 0; i < 8; ++i) {
    const int c = cnt[i];
    const int bl = ((c + 255) >> 8) << LOGNB;
    if (e < 0) {
      if (loc < bl) { e = i; cnte = c; }
      else { loc -= bl; pre += c; }
    }
  }
  if (e < 0) return;
  const int row0 = (loc >> LOGNB) << 8;
  const int n0   = (loc & (NB - 1)) << 8;

  const int tid = threadIdx.x;
  const int lane = tid & 63, wid = tid >> 6;
  const int wr = wid >> 2, wc = wid & 3;     // wave output: rows wr*128, cols wc*64
  const int l15 = lane & 15;

  if (tid < 256) {
    const int s = row0 + tid;
    if (s < cnte) {
      const int t = list[e * 16384 + s];
      tok_s[tid] = t;
      wt_s[tid]  = (EPI == 2) ? wts[t] : 0.f;
    } else { tok_s[tid] = 0; wt_s[tid] = 0.f; }
  }
  __syncthreads();

  // ---- staging: thread covers rows {srow, 128+srow}, 16B slot (tid&3)
  const int srow = tid >> 2;                 // 0..127
  const int gch  = ((tid & 3) ^ ((srow >> 1) & 3)) * 8;   // pre-swizzled chunk
  const unsigned short* aG0;
  const unsigned short* aG1;
  if (EPI == 1) {                            // gathered token rows
    aG0 = A + (size_t)tok_s[srow] * K + gch;
    aG1 = A + (size_t)tok_s[128 + srow] * K + gch;
  } else {                                   // dense slot rows
    aG0 = A + (size_t)min(pre + row0 + srow, 16383) * K + gch;
    aG1 = A + (size_t)min(pre + row0 + 128 + srow, 16383) * K + gch;
  }
  const unsigned short* bG0 = Bt + ((size_t)e * N + n0 + srow) * K + gch;
  const unsigned short* bG1 = Bt + ((size_t)e * N + n0 + 128 + srow) * K + gch;

  // ---- fragment read bases (XOR folds to per-lane constant)
  const int xo = (((lane >> 4) ^ ((l15 >> 1) & 3)) << 4);
  const char* aB = lds + wr * 8192 + l15 * 64 + xo;           // + slot*16384 + m*1024
  const char* bB = lds + 65536 + wc * 4096 + l15 * 64 + xo;   // + slot*16384 + n*1024

  f32x4 acc[8][4];
#pragma unroll
  for (int m = 0; m < 8; ++m)
#pragma unroll
    for (int n = 0; n < 4; ++n) acc[m][n] = (f32x4){0.f, 0.f, 0.f, 0.f};

#define STG_A(S, T) do { \
    char* d_ = lds + (S) * 16384 + (wid << 10); \
    gload16(aG0 + (size_t)(T) * 32, d_); \
    gload16(aG1 + (size_t)(T) * 32, d_ + 8192); } while (0)
#define STG_B(S, T) do { \
    char* d_ = lds + 65536 + (S) * 16384 + (wid << 10); \
    gload16(bG0 + (size_t)(T) * 32, d_); \
    gload16(bG1 + (size_t)(T) * 32, d_ + 8192); } while (0)

  // one iteration: read frags(T+1) into AN/BN, stage T+3, MFMA on AC/BC
#define TILE_BODY(AC, BC, AN, BN, T) do { \
    const int Tn_ = ((T) + 1 < NT) ? (T) + 1 : NT - 1; \
    const char* aR_ = aB + (Tn_ & 3) * 16384; \
    const char* bR_ = bB + (Tn_ & 3) * 16384; \
    _Pragma("unroll") \
    for (int m_ = 0; m_ < 8; ++m_) AN[m_] = *(const short8*)(aR_ + m_ * 1024); \
    _Pragma("unroll") \
    for (int n_ = 0; n_ < 4; ++n_) BN[n_] = *(const short8*)(bR_ + n_ * 1024); \
    const int ss_ = ((T) + 3) & 3; \
    const int Ts_ = ((T) + 3 < NT) ? (T) + 3 : NT - 1; \
    STG_A(ss_, Ts_); \
    STG_B(ss_, Ts_); \
    __builtin_amdgcn_sched_barrier(0); \
    __builtin_amdgcn_s_setprio(1); \
    _Pragma("unroll") \
    for (int m_ = 0; m_ < 8; ++m_) \
      _Pragma("unroll") \
      for (int n_ = 0; n_ < 4; ++n_) \
        acc[m_][n_] = __builtin_amdgcn_mfma_f32_16x16x32_bf16( \
            AC[m_], BC[n_], acc[m_][n_], 0, 0, 0); \
    __builtin_amdgcn_s_setprio(0); \
    __builtin_amdgcn_sched_barrier(0); \
    asm volatile("s_waitcnt vmcnt(4)" ::: "memory"); \
    __builtin_amdgcn_s_barrier(); \
  } while (0)

  // ---- prologue: stage tiles 0,1,2; certify tiles 0,1; preload frags(0)
  STG_A(0, 0); STG_B(0, 0);
  STG_A(1, 1); STG_B(1, 1);
  STG_A(2, 2); STG_B(2, 2);
  asm volatile("s_waitcnt vmcnt(4)" ::: "memory");   // tiles 0,1 certified
  __builtin_amdgcn_s_barrier();

  short8 aX[8], bX[4], aY[8], bY[4];
#pragma unroll
  for (int m = 0; m < 8; ++m) aX[m] = *(const short8*)(aB + m * 1024);
#pragma unroll
  for (int n = 0; n < 4; ++n) bX[n] = *(const short8*)(bB + n * 1024);

#pragma unroll 1
  for (int T = 0; T < NT; T += 2) {
    TILE_BODY(aX, bX, aY, bY, T);
    TILE_BODY(aY, bY, aX, bX, T + 1);
  }
#undef TILE_BODY
#undef STG_A
#undef STG_B
  asm volatile("s_waitcnt vmcnt(0) lgkmcnt(0)" ::: "memory");  // drain dummies

  // ---- epilogue; C frag: col = lane&15, row = (lane>>4)*4 + r
  const int cRow0 = wr * 128 + ((lane >> 4) << 2);
  const int cColB = n0 + wc * 64 + l15;
  float bv[4];
#pragma unroll
  for (int nf = 0; nf < 4; ++nf) bv[nf] = bias[e * N + cColB + nf * 16];

  if (EPI == 1) {
    unsigned short* H = (unsigned short*)outp;
#pragma unroll
    for (int m = 0; m < 8; ++m)
#pragma unroll
      for (int r = 0; r < 4; ++r) {
        const int sl = cRow0 + m * 16 + r;
        if (row0 + sl < cnte) {
          const size_t rp = (size_t)(pre + row0 + sl) * N + cColB;
#pragma unroll
          for (int nf = 0; nf < 4; ++nf) {
            float v = acc[m][nf][r] + bv[nf];
            // tanh-form GELU via exp (dev <= ~1e-3 vs erf; threshold 3.4e-2)
            float u = 1.5957691216f * v * (1.0f + 0.044715f * v * v);
            float ex = __expf(u);
            float th = 1.0f - 2.0f / (ex + 1.0f);
            v = 0.5f * v * (1.0f + th);
            H[rp + nf * 16] = f2b(v);
          }
        }
      }
  } else {
    float* O = (float*)outp;
#pragma unroll
    for (int m = 0; m < 8; ++m)
#pragma unroll
      for (int r = 0; r < 4; ++r) {
        const int sl = cRow0 + m * 16 + r;
        if (row0 + sl < cnte) {
          const size_t rp = (size_t)tok_s[sl] * N + cColB;
          const float w = wt_s[sl];
#pragma unroll
          for (int nf = 0; nf < 4; ++nf)
            O[rp + nf * 16] = (acc[m][nf][r] + bv[nf]) * w;
        }
      }
  }
}

// ---------------------------------------------------------------------------
extern "C" void kernel_launch(void* const* d_in, const int* in_sizes, int n_in,
                              void* d_out, int out_size, void* d_ws, size_t ws_size,
                              hipStream_t stream) {
  const float* x  = (const float*)d_in[0];   // [4,4096,1024]
  const float* Wr = (const float*)d_in[1];   // [1024,8]
  const float* br = (const float*)d_in[2];   // [8]
  const float* W1 = (const float*)d_in[3];   // [8,1024,2048]
  const float* b1 = (const float*)d_in[4];   // [8,2048]
  const float* W2 = (const float*)d_in[5];   // [8,2048,1024]
  const float* b2 = (const float*)d_in[6];   // [8,1024]

  char* ws = (char*)d_ws;
  int*   cnt  = (int*)ws;                                  // 8 ints
  float* wts  = (float*)(ws + 256);                        // 16384 f32
  int*   eidx = (int*)(ws + 256 + 64 * 1024);              // 16384 int
  int*   list = (int*)(ws + 256 + 128 * 1024);             // 8*16384 int
  unsigned short* xb  = (unsigned short*)(ws + 1024 * 1024);     // 32 MB token rows
  unsigned short* w1t = xb  + (size_t)16384 * 1024;              // 32 MB
  unsigned short* w2t = w1t + (size_t)8 * 2048 * 1024;           // 32 MB
  unsigned short* h   = w2t + (size_t)8 * 1024 * 2048;           // 64 MB slot rows

  constexpr int LDS_BYTES = 133120;
  hipFuncSetAttribute((const void*)gemm_moe8<1024, 2048, 1, 3>,
                      hipFuncAttributeMaxDynamicSharedMemorySize, LDS_BYTES);
  hipFuncSetAttribute((const void*)gemm_moe8<2048, 1024, 2, 2>,
                      hipFuncAttributeMaxDynamicSharedMemorySize, LDS_BYTES);

  hipMemsetAsync(cnt, 0, 32, stream);
  router_logits<<<dim3(4096), 256, 0, stream>>>(x, Wr, br, wts, eidx, xb);
  bucketize<<<dim3(64), 256, 0, stream>>>(eidx, cnt, list);
  transpose_cvt<<<dim3(32, 16, 8), 256, 0, stream>>>(W1, w1t, 1024, 2048);
  transpose_cvt<<<dim3(16, 32, 8), 256, 0, stream>>>(W2, w2t, 2048, 1024);
  // worst-case m-blocks: sum_e ceil(cnt_e/256) <= 64+7 = 71
  gemm_moe8<1024, 2048, 1, 3><<<dim3(71 * 8), 512, LDS_BYTES, stream>>>(
      xb, w1t, b1, cnt, list, wts, (void*)h);
  gemm_moe8<2048, 1024, 2, 2><<<dim3(71 * 4), 512, LDS_BYTES, stream>>>(
      h, w2t, b2, cnt, list, wts, d_out);
}